// Round 10
// baseline (288.821 us; speedup 1.0000x reference)
//
#include <hip/hip_runtime.h>
#include <stdint.h>

typedef unsigned long long u64;
typedef u64 u64x2 __attribute__((ext_vector_type(2)));

// key: ((b*41+z)<<20) | y<<10 | x   (b<4, z<41, y,x<1024)
// -> 164*2^20 = 171,966,464 keys; monotone-equivalent to reference hash
// b*1025^3+z*1025^2+y*1025+x (lex order (b,z,y,x) preserved, bijective).
#define NWORDS 2686976u             // 164*2^20/64 words
#define GW 4096u                    // words per block (256 thr x 16 words)
#define NGROUPS 656u                // NWORDS/GW (exact)

// interleaved per-word record: presence bits + exclusive rank prefix.
// One teacher probe = ONE random 16B load (global_load_dwordx4) = one line touch.
struct __align__(16) Combo { u64 word; uint32_t prefix; uint32_t pad; };

__device__ __forceinline__ uint32_t pack4(int4 v) {
    // v = (b, z, y, x)
    return (((uint32_t)v.x * 41u + (uint32_t)v.y) << 20) |
           ((uint32_t)v.z << 10) | (uint32_t)v.w;
}

// ---------------- phase 1: presence bits ----------------
// Fire-and-forget atomicOr only (round-6 lesson: no contended counters, no return use).
__global__ void set_bits(const int* __restrict__ sidx, Combo* __restrict__ combo, int ns) {
    int i = blockIdx.x * blockDim.x + threadIdx.x;
    if (i >= ns) return;
    uint32_t k = pack4(((const int4*)sidx)[i]);
    atomicOr(&combo[k >> 6].word, 1ull << (k & 63u));
}

// ---------------- phase 2 (fused): rank + prefix + sorted decoded indice ----------------
// Decoupled lookback across the 656 blocks: publish (1<<32)|blockTotal with a
// device-scope release store; wave 0 sums all predecessor aggregates (64-lane
// parallel, brief spin on unpublished). Integer sums -> deterministic.
// All 656 blocks co-resident (4 waves, 1KB LDS) -> no scheduling deadlock.
__global__ void prefix_emit(Combo* __restrict__ combo, u64* __restrict__ state,
                            float* __restrict__ outI) {
    __shared__ uint32_t s[256];
    __shared__ uint32_t baseSh;
    const int tid = threadIdx.x, bid = blockIdx.x;
    const size_t w0 = (size_t)bid * GW + (size_t)tid * 16;

    u64 w[16];
    uint32_t tsum = 0;
    #pragma unroll
    for (int j = 0; j < 16; ++j) { w[j] = combo[w0 + j].word; tsum += (uint32_t)__popcll(w[j]); }

    // block-inclusive scan of per-thread popcounts
    s[tid] = tsum;
    __syncthreads();
    #pragma unroll
    for (int off = 1; off < 256; off <<= 1) {
        uint32_t u = (tid >= off) ? s[tid - off] : 0u;
        __syncthreads();
        s[tid] += u;
        __syncthreads();
    }
    uint32_t exclInBlock = s[tid] - tsum;

    // publish this block's aggregate immediately
    if (tid == 0)
        __hip_atomic_store(&state[bid], (1ull << 32) | (u64)s[255],
                           __ATOMIC_RELEASE, __HIP_MEMORY_SCOPE_AGENT);

    // wave 0: sum aggregates of all preceding blocks (independent loads, short spin)
    if (tid == 0) baseSh = 0u;   // default for bid==0 (overwritten below otherwise)
    if (bid > 0 && tid < 64) {
        uint32_t sum = 0;
        for (int i = bid - 1 - tid; i >= 0; i -= 64) {
            u64 st;
            do {
                st = __hip_atomic_load(&state[i], __ATOMIC_ACQUIRE, __HIP_MEMORY_SCOPE_AGENT);
            } while ((st >> 32) == 0ull);
            sum += (uint32_t)st;
        }
        #pragma unroll
        for (int off = 32; off > 0; off >>= 1) sum += __shfl_down(sum, off);
        if (tid == 0) baseSh = sum;
    }
    __syncthreads();
    uint32_t run = baseSh + exclInBlock;

    // store full 16B records (fully-dirty lines; round-8 lesson) + emit sorted indice
    #pragma unroll
    for (int j = 0; j < 16; ++j) {
        u64x2 rec; rec.x = w[j]; rec.y = (u64)run;   // low 32 of .y = prefix
        ((u64x2*)combo)[w0 + j] = rec;
        u64 word = w[j];
        uint32_t kw = (uint32_t)(w0 + j) << 6;
        while (word) {
            int b = (int)__builtin_ctzll(word);
            word &= word - 1;
            uint32_t k = kw | (uint32_t)b;
            uint32_t bz = k >> 20;
            ((float4*)outI)[run++] = make_float4(
                (float)(bz / 41u), (float)(bz % 41u),
                (float)((k >> 10) & 1023u), (float)(k & 1023u));
        }
    }
}

// ---------------- phase 3: teacher probe — 2 rows/thread for MLP ----------------
__device__ __forceinline__ void probe_one(uint32_t k, u64x2 e, uint32_t* cnt, int* pos, int t) {
    u64 word = e.x;
    u64 bit  = 1ull << (k & 63u);
    if (word & bit) {
        int p = (int)((uint32_t)e.y + (uint32_t)__popcll(word & (bit - 1ull)));
        pos[t] = p;
        atomicAdd(&cnt[p], 1u);   // ~2M atomics over ~25K lines: negligible serialization
    } else {
        pos[t] = -1;
    }
}

__global__ void teacher_probe(const int* __restrict__ tidx, const Combo* __restrict__ combo,
                              uint32_t* __restrict__ cnt, int* __restrict__ pos, int nt) {
    int i = blockIdx.x * blockDim.x + threadIdx.x;
    int t0 = i * 2, t1 = i * 2 + 1;
    if (t0 >= nt) return;
    uint32_t k0 = pack4(((const int4*)tidx)[t0]);
    u64x2 e0 = ((const u64x2*)combo)[k0 >> 6];           // issue both random loads
    if (t1 < nt) {
        uint32_t k1 = pack4(((const int4*)tidx)[t1]);
        u64x2 e1 = ((const u64x2*)combo)[k1 >> 6];
        probe_one(k0, e0, cnt, pos, t0);
        probe_one(k1, e1, cnt, pos, t1);
    } else {
        probe_one(k0, e0, cnt, pos, t0);
    }
}

// zero only multi-contributor rows; cnt==1 rows are fully overwritten by plain stores
__global__ void zero_multi(const uint32_t* __restrict__ cnt, float* __restrict__ feat, int ns) {
    int s = blockIdx.x * blockDim.x + threadIdx.x;
    if (s >= ns) return;
    if (cnt[s] > 1u) {
        float4* d4 = (float4*)(feat + (size_t)s * 32);
        #pragma unroll
        for (int q = 0; q < 8; ++q) d4[q] = make_float4(0.f, 0.f, 0.f, 0.f);
    }
}

// ---------------- phase 4: feature write — 2 rows/thread for MLP ----------------
__device__ __forceinline__ void write_one(const float* __restrict__ tfeat, int t, int p,
                                          const uint32_t* __restrict__ cnt,
                                          float* __restrict__ feat) {
    const float4* src = (const float4*)(tfeat + (size_t)t * 32);
    float* dst = feat + (size_t)p * 32;
    if (cnt[p] == 1u) {
        float4* d4 = (float4*)dst;
        #pragma unroll
        for (int q = 0; q < 8; ++q) d4[q] = src[q];
    } else {
        #pragma unroll
        for (int q = 0; q < 8; ++q) {
            float4 f = src[q];
            atomicAdd(dst + q * 4 + 0, f.x);
            atomicAdd(dst + q * 4 + 1, f.y);
            atomicAdd(dst + q * 4 + 2, f.z);
            atomicAdd(dst + q * 4 + 3, f.w);
        }
    }
}

__global__ void teacher_write(const float* __restrict__ tfeat, const int* __restrict__ pos,
                              const uint32_t* __restrict__ cnt, float* __restrict__ feat, int nt) {
    int i = blockIdx.x * blockDim.x + threadIdx.x;
    int t0 = i * 2, t1 = i * 2 + 1;
    if (t0 >= nt) return;
    int2 pp = (t1 < nt) ? *(const int2*)(pos + t0) : make_int2(pos[t0], -1);
    if (pp.x >= 0) write_one(tfeat, t0, pp.x, cnt, feat);
    if (pp.y >= 0) write_one(tfeat, t1, pp.y, cnt, feat);
}

extern "C" void kernel_launch(void* const* d_in, const int* in_sizes, int n_in,
                              void* d_out, int out_size, void* d_ws, size_t ws_size,
                              hipStream_t stream) {
    const float* tfeat = (const float*)d_in[0];
    const int*   tidx  = (const int*)d_in[1];
    const int*   sidx  = (const int*)d_in[2];

    const int NT = in_sizes[1] / 4;
    const int NS = in_sizes[2] / 4;

    float* feat = (float*)d_out;                        // [NS, 32]
    float* outI = (float*)d_out + (size_t)NS * 32;      // [NS, 4] as floats

    // workspace: [combo 41MiB][cnt NS*4][state 656*8] <- one contiguous zero-fill
    //            [pos NT*4]                              (~54MB << ~1GB ws)
    char* base = (char*)d_ws;
    Combo*    combo = (Combo*)base;
    uint32_t* cnt   = (uint32_t*)(base + (size_t)NWORDS * sizeof(Combo));
    u64*      state = (u64*)(cnt + NS);
    int*      pos   = (int*)(state + NGROUPS);
    size_t zeroBytes = (size_t)NWORDS * sizeof(Combo) + (size_t)NS * 4 + (size_t)NGROUPS * 8;

    hipMemsetAsync(d_ws, 0, zeroBytes, stream);

    set_bits<<<(NS + 255) / 256, 256, 0, stream>>>(sidx, combo, NS);
    prefix_emit<<<NGROUPS, 256, 0, stream>>>(combo, state, outI);
    int halfT = (NT + 1) / 2;
    teacher_probe<<<(halfT + 255) / 256, 256, 0, stream>>>(tidx, combo, cnt, pos, NT);
    zero_multi<<<(NS + 255) / 256, 256, 0, stream>>>(cnt, feat, NS);
    teacher_write<<<(halfT + 255) / 256, 256, 0, stream>>>(tfeat, pos, cnt, feat, NT);
}

// Round 11
// 238.097 us; speedup vs baseline: 1.2130x; 1.2130x over previous
//
#include <hip/hip_runtime.h>
#include <stdint.h>

typedef unsigned long long u64;
typedef u64 u64x2 __attribute__((ext_vector_type(2)));

// key: ((b*41+z)<<20) | y<<10 | x   (b<4, z<41, y,x<1024)
// -> 164*2^20 = 171,966,464 keys; monotone-equivalent to reference hash
// b*1025^3+z*1025^2+y*1025+x (lex order (b,z,y,x) preserved, bijective).
#define NWORDS 2686976u             // 164*2^20/64 words
#define GW 4096u                    // words per block (256 thr x 16 words)
#define NGROUPS 656u                // NWORDS/GW (exact)

// interleaved per-word record: presence bits + exclusive rank prefix.
// One teacher probe = ONE random 16B load (global_load_dwordx4) = one line touch.
struct __align__(16) Combo { u64 word; uint32_t prefix; uint32_t pad; };

__device__ __forceinline__ uint32_t pack4(int4 v) {
    // v = (b, z, y, x)
    return (((uint32_t)v.x * 41u + (uint32_t)v.y) << 20) |
           ((uint32_t)v.z << 10) | (uint32_t)v.w;
}

// ---------------- phase 1: presence bits ----------------
// Fire-and-forget atomicOr only (round-6 lesson: no contended counters, no return use).
__global__ void set_bits(const int* __restrict__ sidx, Combo* __restrict__ combo, int ns) {
    int i = blockIdx.x * blockDim.x + threadIdx.x;
    if (i >= ns) return;
    uint32_t k = pack4(((const int4*)sidx)[i]);
    atomicOr(&combo[k >> 6].word, 1ull << (k & 63u));
}

// ---------------- phase 2: per-group bit counts (wave-coalesced streaming reads) ----------------
__global__ void group_popcount(const Combo* __restrict__ combo, uint32_t* __restrict__ groupSum) {
    __shared__ uint32_t s[256];
    uint32_t t = 0;
    size_t base = (size_t)blockIdx.x * GW;
    #pragma unroll
    for (int j = 0; j < 16; ++j)
        t += (uint32_t)__popcll(combo[base + j * 256u + threadIdx.x].word);
    s[threadIdx.x] = t;
    __syncthreads();
    #pragma unroll
    for (int off = 128; off > 0; off >>= 1) {
        if (threadIdx.x < (unsigned)off) s[threadIdx.x] += s[threadIdx.x + off];
        __syncthreads();
    }
    if (threadIdx.x == 0) groupSum[blockIdx.x] = s[0];
}

// single block: exclusive scan of NGROUPS group sums
__global__ void scan_groups(uint32_t* __restrict__ groupSum, int n) {
    __shared__ uint32_t s[256];
    uint32_t run = 0;
    for (int c = 0; c < n; c += 256) {
        int i = c + (int)threadIdx.x;
        uint32_t v = (i < n) ? groupSum[i] : 0u;
        s[threadIdx.x] = v;
        __syncthreads();
        #pragma unroll
        for (int off = 1; off < 256; off <<= 1) {
            uint32_t u = (threadIdx.x >= (unsigned)off) ? s[threadIdx.x - off] : 0u;
            __syncthreads();
            s[threadIdx.x] += u;
            __syncthreads();
        }
        if (i < n) groupSum[i] = s[threadIdx.x] - v + run;
        run += s[255];
        __syncthreads();
    }
}

// ---------------- phase 3: per-word prefix + sorted decoded indice ----------------
// Thread owns 16 CONTIGUOUS words (rank order == thread order). Stores the FULL
// 16B Combo record (word re-stored with its prefix) so lines become fully dirty —
// avoids partial-line RMW writebacks (round-8 lesson).
__global__ void word_prefix_indice(Combo* __restrict__ combo,
                                   const uint32_t* __restrict__ groupBase,
                                   float* __restrict__ outI) {
    __shared__ uint32_t s[256];
    const int tid = threadIdx.x;
    size_t w0 = (size_t)blockIdx.x * GW + (size_t)tid * 16;
    u64 w[16];
    uint32_t tsum = 0;
    #pragma unroll
    for (int j = 0; j < 16; ++j) { w[j] = combo[w0 + j].word; tsum += (uint32_t)__popcll(w[j]); }
    s[tid] = tsum;
    __syncthreads();
    #pragma unroll
    for (int off = 1; off < 256; off <<= 1) {
        uint32_t u = (tid >= off) ? s[tid - off] : 0u;
        __syncthreads();
        s[tid] += u;
        __syncthreads();
    }
    uint32_t run = groupBase[blockIdx.x] + s[tid] - tsum;   // exclusive rank at first word
    #pragma unroll
    for (int j = 0; j < 16; ++j) {
        u64x2 rec; rec.x = w[j]; rec.y = (u64)run;          // low 32 of .y = prefix
        ((u64x2*)combo)[w0 + j] = rec;
        u64 word = w[j];
        uint32_t kw = (uint32_t)(w0 + j) << 6;
        while (word) {
            int b = (int)__builtin_ctzll(word);
            word &= word - 1;
            uint32_t k = kw | (uint32_t)b;
            uint32_t bz = k >> 20;
            ((float4*)outI)[run++] = make_float4(
                (float)(bz / 41u), (float)(bz % 41u),
                (float)((k >> 10) & 1023u), (float)(k & 1023u));
        }
    }
}

// ---------------- phase 4: teacher probe — 2 rows/thread for MLP ----------------
__device__ __forceinline__ void probe_one(uint32_t k, u64x2 e, uint32_t* cnt, int* pos, int t) {
    u64 word = e.x;
    u64 bit  = 1ull << (k & 63u);
    if (word & bit) {
        int p = (int)((uint32_t)e.y + (uint32_t)__popcll(word & (bit - 1ull)));
        pos[t] = p;
        atomicAdd(&cnt[p], 1u);   // ~2M atomics over ~25K lines: negligible serialization
    } else {
        pos[t] = -1;
    }
}

__global__ void teacher_probe(const int* __restrict__ tidx, const Combo* __restrict__ combo,
                              uint32_t* __restrict__ cnt, int* __restrict__ pos, int nt) {
    int i = blockIdx.x * blockDim.x + threadIdx.x;
    int t0 = i * 2, t1 = i * 2 + 1;
    if (t0 >= nt) return;
    uint32_t k0 = pack4(((const int4*)tidx)[t0]);
    u64x2 e0 = ((const u64x2*)combo)[k0 >> 6];           // issue both random loads
    if (t1 < nt) {
        uint32_t k1 = pack4(((const int4*)tidx)[t1]);
        u64x2 e1 = ((const u64x2*)combo)[k1 >> 6];
        probe_one(k0, e0, cnt, pos, t0);
        probe_one(k1, e1, cnt, pos, t1);
    } else {
        probe_one(k0, e0, cnt, pos, t0);
    }
}

// zero only multi-contributor rows; cnt==1 rows are fully overwritten by plain stores
__global__ void zero_multi(const uint32_t* __restrict__ cnt, float* __restrict__ feat, int ns) {
    int s = blockIdx.x * blockDim.x + threadIdx.x;
    if (s >= ns) return;
    if (cnt[s] > 1u) {
        float4* d4 = (float4*)(feat + (size_t)s * 32);
        #pragma unroll
        for (int q = 0; q < 8; ++q) d4[q] = make_float4(0.f, 0.f, 0.f, 0.f);
    }
}

// ---------------- phase 5: feature write — 2 rows/thread for MLP ----------------
__device__ __forceinline__ void write_one(const float* __restrict__ tfeat, int t, int p,
                                          const uint32_t* __restrict__ cnt,
                                          float* __restrict__ feat) {
    const float4* src = (const float4*)(tfeat + (size_t)t * 32);
    float* dst = feat + (size_t)p * 32;
    if (cnt[p] == 1u) {
        float4* d4 = (float4*)dst;
        #pragma unroll
        for (int q = 0; q < 8; ++q) d4[q] = src[q];
    } else {
        #pragma unroll
        for (int q = 0; q < 8; ++q) {
            float4 f = src[q];
            atomicAdd(dst + q * 4 + 0, f.x);
            atomicAdd(dst + q * 4 + 1, f.y);
            atomicAdd(dst + q * 4 + 2, f.z);
            atomicAdd(dst + q * 4 + 3, f.w);
        }
    }
}

__global__ void teacher_write(const float* __restrict__ tfeat, const int* __restrict__ pos,
                              const uint32_t* __restrict__ cnt, float* __restrict__ feat, int nt) {
    int i = blockIdx.x * blockDim.x + threadIdx.x;
    int t0 = i * 2, t1 = i * 2 + 1;
    if (t0 >= nt) return;
    int2 pp = (t1 < nt) ? *(const int2*)(pos + t0) : make_int2(pos[t0], -1);
    if (pp.x >= 0) write_one(tfeat, t0, pp.x, cnt, feat);
    if (pp.y >= 0) write_one(tfeat, t1, pp.y, cnt, feat);
}

extern "C" void kernel_launch(void* const* d_in, const int* in_sizes, int n_in,
                              void* d_out, int out_size, void* d_ws, size_t ws_size,
                              hipStream_t stream) {
    const float* tfeat = (const float*)d_in[0];
    const int*   tidx  = (const int*)d_in[1];
    const int*   sidx  = (const int*)d_in[2];

    const int NT = in_sizes[1] / 4;
    const int NS = in_sizes[2] / 4;

    float* feat = (float*)d_out;                        // [NS, 32]
    float* outI = (float*)d_out + (size_t)NS * 32;      // [NS, 4] as floats

    // workspace: [combo 41MiB][cnt NS*4] <- one contiguous zero-fill
    //            [groupSum 656*4][pos NT*4]            (~54MB << ~1GB ws)
    char* base = (char*)d_ws;
    Combo*    combo    = (Combo*)base;
    uint32_t* cnt      = (uint32_t*)(base + (size_t)NWORDS * sizeof(Combo));
    size_t    zeroBytes = (size_t)NWORDS * sizeof(Combo) + (size_t)NS * 4;
    uint32_t* groupSum = cnt + NS;
    int*      pos      = (int*)(groupSum + NGROUPS);

    hipMemsetAsync(d_ws, 0, zeroBytes, stream);

    set_bits<<<(NS + 255) / 256, 256, 0, stream>>>(sidx, combo, NS);
    group_popcount<<<NGROUPS, 256, 0, stream>>>(combo, groupSum);
    scan_groups<<<1, 256, 0, stream>>>(groupSum, NGROUPS);
    word_prefix_indice<<<NGROUPS, 256, 0, stream>>>(combo, groupSum, outI);
    int halfT = (NT + 1) / 2;
    teacher_probe<<<(halfT + 255) / 256, 256, 0, stream>>>(tidx, combo, cnt, pos, NT);
    zero_multi<<<(NS + 255) / 256, 256, 0, stream>>>(cnt, feat, NS);
    teacher_write<<<(halfT + 255) / 256, 256, 0, stream>>>(tfeat, pos, cnt, feat, NT);
}

// Round 12
// 226.156 us; speedup vs baseline: 1.2771x; 1.0528x over previous
//
#include <hip/hip_runtime.h>
#include <stdint.h>

typedef unsigned long long u64;
typedef u64 u64x2 __attribute__((ext_vector_type(2)));

// key: ((b*41+z)<<20) | y<<10 | x   (b<4, z<41, y,x<1024)
// -> 164*2^20 = 171,966,464 keys; monotone-equivalent to reference hash
// b*1025^3+z*1025^2+y*1025+x (lex order (b,z,y,x) preserved, bijective).
#define NWORDS 2686976u             // 164*2^20/64 words
#define GW 4096u                    // words per block (256 thr x 16 words)
#define NGROUPS 656u                // NWORDS/GW (exact)

// interleaved per-word record: presence bits + exclusive rank prefix.
// One teacher probe = ONE random 16B load (global_load_dwordx4) = one line touch.
struct __align__(16) Combo { u64 word; uint32_t prefix; uint32_t pad; };

__device__ __forceinline__ uint32_t pack4(int4 v) {
    // v = (b, z, y, x)
    return (((uint32_t)v.x * 41u + (uint32_t)v.y) << 20) |
           ((uint32_t)v.z << 10) | (uint32_t)v.w;
}

// ---------------- phase 1: presence bits ----------------
// Fire-and-forget atomicOr only (round-6 lesson: no contended counters, no return use).
__global__ void set_bits(const int* __restrict__ sidx, Combo* __restrict__ combo, int ns) {
    int i = blockIdx.x * blockDim.x + threadIdx.x;
    if (i >= ns) return;
    uint32_t k = pack4(((const int4*)sidx)[i]);
    atomicOr(&combo[k >> 6].word, 1ull << (k & 63u));
}

// ---------------- phase 2: per-group bit counts (wave-coalesced streaming reads) ----------------
__global__ void group_popcount(const Combo* __restrict__ combo, uint32_t* __restrict__ groupSum) {
    __shared__ uint32_t s[256];
    uint32_t t = 0;
    size_t base = (size_t)blockIdx.x * GW;
    #pragma unroll
    for (int j = 0; j < 16; ++j)
        t += (uint32_t)__popcll(combo[base + j * 256u + threadIdx.x].word);
    s[threadIdx.x] = t;
    __syncthreads();
    #pragma unroll
    for (int off = 128; off > 0; off >>= 1) {
        if (threadIdx.x < (unsigned)off) s[threadIdx.x] += s[threadIdx.x + off];
        __syncthreads();
    }
    if (threadIdx.x == 0) groupSum[blockIdx.x] = s[0];
}

// ---------------- phase 3: per-word prefix + sorted decoded indice ----------------
// groupSum entries are FINALIZED by the kernel boundary, so each block sums its
// predecessors directly (656 u32, L2-hot; wave 0, no spinning — round-10 lesson:
// no intra-kernel producer-consumer across XCDs). Replaces the scan_groups launch.
// Stores the FULL 16B Combo record (fully-dirty lines; round-8 lesson).
__global__ void word_prefix_indice(Combo* __restrict__ combo,
                                   const uint32_t* __restrict__ groupSum,
                                   float* __restrict__ outI) {
    __shared__ uint32_t s[256];
    __shared__ uint32_t baseSh;
    const int tid = threadIdx.x, bid = blockIdx.x;
    size_t w0 = (size_t)bid * GW + (size_t)tid * 16;
    u64 w[16];
    uint32_t tsum = 0;
    #pragma unroll
    for (int j = 0; j < 16; ++j) { w[j] = combo[w0 + j].word; tsum += (uint32_t)__popcll(w[j]); }
    s[tid] = tsum;
    __syncthreads();
    #pragma unroll
    for (int off = 1; off < 256; off <<= 1) {
        uint32_t u = (tid >= off) ? s[tid - off] : 0u;
        __syncthreads();
        s[tid] += u;
        __syncthreads();
    }
    uint32_t exclInBlock = s[tid] - tsum;
    // wave 0: sum of preceding blocks' totals (empty loop for bid==0 -> 0)
    if (tid < 64) {
        uint32_t sum = 0;
        for (int g = tid; g < bid; g += 64) sum += groupSum[g];
        #pragma unroll
        for (int off = 32; off > 0; off >>= 1) sum += __shfl_down(sum, off);
        if (tid == 0) baseSh = sum;
    }
    __syncthreads();
    uint32_t run = baseSh + exclInBlock;   // exclusive rank at this thread's first word
    #pragma unroll
    for (int j = 0; j < 16; ++j) {
        u64x2 rec; rec.x = w[j]; rec.y = (u64)run;          // low 32 of .y = prefix
        ((u64x2*)combo)[w0 + j] = rec;
        u64 word = w[j];
        uint32_t kw = (uint32_t)(w0 + j) << 6;
        while (word) {
            int b = (int)__builtin_ctzll(word);
            word &= word - 1;
            uint32_t k = kw | (uint32_t)b;
            uint32_t bz = k >> 20;
            ((float4*)outI)[run++] = make_float4(
                (float)(bz / 41u), (float)(bz % 41u),
                (float)((k >> 10) & 1023u), (float)(k & 1023u));
        }
    }
}

// ---------------- phase 4: fused teacher pass (claim-based) ----------------
// Probe -> claim via atomicAdd return. Winner (old==0) plain-stores the 128B row
// (overwrites any stale data -> no feat pre-zeroing). Losers (~46K of 2M) append
// (t,p) to an overflow list, drained by the next kernel (ordering via kernel
// boundary). 2-contributor sums are commutative-exact; >=3 rows are ~dozens.
__global__ void teacher_fused(const int* __restrict__ tidx, const float* __restrict__ tfeat,
                              const Combo* __restrict__ combo, uint32_t* __restrict__ cnt,
                              uint2* __restrict__ ovf, uint32_t* __restrict__ ovfCount,
                              float* __restrict__ feat, int nt) {
    int t = blockIdx.x * blockDim.x + threadIdx.x;
    if (t >= nt) return;
    uint32_t k = pack4(((const int4*)tidx)[t]);
    u64x2 e = ((const u64x2*)combo)[k >> 6];
    u64 word = e.x;
    u64 bit  = 1ull << (k & 63u);
    if (!(word & bit)) return;
    int p = (int)((uint32_t)e.y + (uint32_t)__popcll(word & (bit - 1ull)));
    uint32_t old = atomicAdd(&cnt[p], 1u);
    if (old == 0u) {
        const float4* src = (const float4*)(tfeat + (size_t)t * 32);
        float4* dst = (float4*)(feat + (size_t)p * 32);
        #pragma unroll
        for (int q = 0; q < 8; ++q) dst[q] = src[q];
    } else {
        uint32_t idx = atomicAdd(ovfCount, 1u);
        ovf[idx] = make_uint2((uint32_t)t, (uint32_t)p);
    }
}

// ---------------- phase 5: drain overflow (rare duplicate contributors) ----------------
__global__ void drain_ovf(const float* __restrict__ tfeat, const uint2* __restrict__ ovf,
                          const uint32_t* __restrict__ ovfCount, float* __restrict__ feat) {
    uint32_t n = *ovfCount;
    for (uint32_t i = blockIdx.x * blockDim.x + threadIdx.x; i < n;
         i += gridDim.x * blockDim.x) {
        uint2 e = ovf[i];
        const float4* src = (const float4*)(tfeat + (size_t)e.x * 32);
        float* dst = feat + (size_t)e.y * 32;
        #pragma unroll
        for (int q = 0; q < 8; ++q) {
            float4 f = src[q];
            atomicAdd(dst + q * 4 + 0, f.x);
            atomicAdd(dst + q * 4 + 1, f.y);
            atomicAdd(dst + q * 4 + 2, f.z);
            atomicAdd(dst + q * 4 + 3, f.w);
        }
    }
}

extern "C" void kernel_launch(void* const* d_in, const int* in_sizes, int n_in,
                              void* d_out, int out_size, void* d_ws, size_t ws_size,
                              hipStream_t stream) {
    const float* tfeat = (const float*)d_in[0];
    const int*   tidx  = (const int*)d_in[1];
    const int*   sidx  = (const int*)d_in[2];

    const int NT = in_sizes[1] / 4;
    const int NS = in_sizes[2] / 4;

    float* feat = (float*)d_out;                        // [NS, 32]
    float* outI = (float*)d_out + (size_t)NS * 32;      // [NS, 4] as floats

    // workspace: [combo 41MiB][cnt NS*4][ovfCount 4 + pad 4] <- one contiguous zero-fill
    //            [groupSum 656*4][ovf NT*8]                     (~62MB << ~1GB ws)
    char* base = (char*)d_ws;
    Combo*    combo    = (Combo*)base;
    uint32_t* cnt      = (uint32_t*)(base + (size_t)NWORDS * sizeof(Combo));
    uint32_t* ovfCount = cnt + NS;
    size_t    zeroBytes = (size_t)NWORDS * sizeof(Combo) + (size_t)NS * 4 + 8;
    uint32_t* groupSum = ovfCount + 2;
    uint2*    ovf      = (uint2*)(groupSum + NGROUPS);

    hipMemsetAsync(d_ws, 0, zeroBytes, stream);

    set_bits<<<(NS + 255) / 256, 256, 0, stream>>>(sidx, combo, NS);
    group_popcount<<<NGROUPS, 256, 0, stream>>>(combo, groupSum);
    word_prefix_indice<<<NGROUPS, 256, 0, stream>>>(combo, groupSum, outI);
    teacher_fused<<<(NT + 255) / 256, 256, 0, stream>>>(tidx, tfeat, combo, cnt,
                                                        ovf, ovfCount, feat, NT);
    drain_ovf<<<512, 256, 0, stream>>>(tfeat, ovf, ovfCount, feat);
}

// Round 13
// 212.740 us; speedup vs baseline: 1.3576x; 1.0631x over previous
//
#include <hip/hip_runtime.h>
#include <stdint.h>

typedef unsigned long long u64;

// key: ((b*41+z)<<20) | y<<10 | x   (b<4, z<41, y,x<1024)
// -> 164*2^20 = 171,966,464 keys; monotone-equivalent to reference hash
// b*1025^3+z*1025^2+y*1025+x (lex order (b,z,y,x) preserved, bijective).
#define NWORDS 2686976u             // 164*2^20/64 words
#define GW 4096u                    // words per block (256 thr x 16 words)
#define NGROUPS 656u                // NWORDS/GW (exact)

__device__ __forceinline__ uint32_t pack4(int4 v) {
    // v = (b, z, y, x)
    return (((uint32_t)v.x * 41u + (uint32_t)v.y) << 20) |
           ((uint32_t)v.z << 10) | (uint32_t)v.w;
}

// ---------------- phase 1: presence bits ----------------
// Fire-and-forget atomicOr only (round-6 lesson: no contended counters, no return use).
// words[] is a bare u64 bitmap (21.5 MB) — round-12 lesson: the probe's two loads
// (word, prefix) are address-independent, so splitting the arrays halves every
// table pass without adding probe latency.
__global__ void set_bits(const int* __restrict__ sidx, u64* __restrict__ words, int ns) {
    int i = blockIdx.x * blockDim.x + threadIdx.x;
    if (i >= ns) return;
    uint32_t k = pack4(((const int4*)sidx)[i]);
    atomicOr(&words[k >> 6], 1ull << (k & 63u));
}

// ---------------- phase 2: per-group bit counts (wave-coalesced streaming reads) ----------------
__global__ void group_popcount(const u64* __restrict__ words, uint32_t* __restrict__ groupSum) {
    __shared__ uint32_t s[256];
    uint32_t t = 0;
    size_t base = (size_t)blockIdx.x * GW;
    #pragma unroll
    for (int j = 0; j < 16; ++j)
        t += (uint32_t)__popcll(words[base + j * 256u + threadIdx.x]);
    s[threadIdx.x] = t;
    __syncthreads();
    #pragma unroll
    for (int off = 128; off > 0; off >>= 1) {
        if (threadIdx.x < (unsigned)off) s[threadIdx.x] += s[threadIdx.x + off];
        __syncthreads();
    }
    if (threadIdx.x == 0) groupSum[blockIdx.x] = s[0];
}

// ---------------- phase 3: per-word prefix + sorted decoded indice ----------------
// groupSum entries are FINALIZED by the kernel boundary (round-10 lesson: no
// intra-kernel cross-XCD producer-consumer spin). prefixArr writes are dense
// 4B x 16 contiguous per thread -> fully-dirty coalesced lines; words[] is
// read-only here (no 43MB rewrite).
__global__ void word_prefix_indice(const u64* __restrict__ words,
                                   const uint32_t* __restrict__ groupSum,
                                   uint32_t* __restrict__ prefixArr,
                                   float* __restrict__ outI) {
    __shared__ uint32_t s[256];
    __shared__ uint32_t baseSh;
    const int tid = threadIdx.x, bid = blockIdx.x;
    size_t w0 = (size_t)bid * GW + (size_t)tid * 16;
    u64 w[16];
    uint32_t tsum = 0;
    #pragma unroll
    for (int j = 0; j < 16; ++j) { w[j] = words[w0 + j]; tsum += (uint32_t)__popcll(w[j]); }
    s[tid] = tsum;
    __syncthreads();
    #pragma unroll
    for (int off = 1; off < 256; off <<= 1) {
        uint32_t u = (tid >= off) ? s[tid - off] : 0u;
        __syncthreads();
        s[tid] += u;
        __syncthreads();
    }
    uint32_t exclInBlock = s[tid] - tsum;
    // wave 0: sum of preceding blocks' totals (empty loop for bid==0 -> 0)
    if (tid < 64) {
        uint32_t sum = 0;
        for (int g = tid; g < bid; g += 64) sum += groupSum[g];
        #pragma unroll
        for (int off = 32; off > 0; off >>= 1) sum += __shfl_down(sum, off);
        if (tid == 0) baseSh = sum;
    }
    __syncthreads();
    uint32_t run = baseSh + exclInBlock;   // exclusive rank at this thread's first word
    #pragma unroll
    for (int j = 0; j < 16; ++j) {
        prefixArr[w0 + j] = run;
        u64 word = w[j];
        uint32_t kw = (uint32_t)(w0 + j) << 6;
        while (word) {
            int b = (int)__builtin_ctzll(word);
            word &= word - 1;
            uint32_t k = kw | (uint32_t)b;
            uint32_t bz = k >> 20;
            ((float4*)outI)[run++] = make_float4(
                (float)(bz / 41u), (float)(bz % 41u),
                (float)((k >> 10) & 1023u), (float)(k & 1023u));
        }
    }
}

// ---------------- phase 4: fused teacher pass (claim-based) ----------------
// Probe: two INDEPENDENT random loads (word 8B, prefix 4B — both addresses from k).
// Matched rows issue the full 128B tfeat gather BEFORE the claim atomic so the
// gather latency overlaps the atomic round-trip. Winner (old==0) plain-stores the
// row (no feat pre-zeroing). Losers (~46K of 2M) append to overflow, drained next
// kernel (ordering via kernel boundary). 2-contributor sums commutative-exact.
__global__ void teacher_fused(const int* __restrict__ tidx, const float* __restrict__ tfeat,
                              const u64* __restrict__ words, const uint32_t* __restrict__ prefixArr,
                              uint32_t* __restrict__ cnt,
                              uint2* __restrict__ ovf, uint32_t* __restrict__ ovfCount,
                              float* __restrict__ feat, int nt) {
    int t = blockIdx.x * blockDim.x + threadIdx.x;
    if (t >= nt) return;
    uint32_t k = pack4(((const int4*)tidx)[t]);
    u64 word = words[k >> 6];                 // independent random loads, issue together
    uint32_t pfx = prefixArr[k >> 6];
    u64 bit = 1ull << (k & 63u);
    if (!(word & bit)) return;
    int p = (int)(pfx + (uint32_t)__popcll(word & (bit - 1ull)));
    // prefetch the full row BEFORE the claim atomic (overlaps ~500cy round-trip)
    const float4* src = (const float4*)(tfeat + (size_t)t * 32);
    float4 f0 = src[0], f1 = src[1], f2 = src[2], f3 = src[3];
    float4 f4 = src[4], f5 = src[5], f6 = src[6], f7 = src[7];
    uint32_t old = atomicAdd(&cnt[p], 1u);
    if (old == 0u) {
        float4* dst = (float4*)(feat + (size_t)p * 32);
        dst[0] = f0; dst[1] = f1; dst[2] = f2; dst[3] = f3;
        dst[4] = f4; dst[5] = f5; dst[6] = f6; dst[7] = f7;
    } else {
        uint32_t idx = atomicAdd(ovfCount, 1u);
        ovf[idx] = make_uint2((uint32_t)t, (uint32_t)p);
    }
}

// ---------------- phase 5: drain overflow (rare duplicate contributors) ----------------
__global__ void drain_ovf(const float* __restrict__ tfeat, const uint2* __restrict__ ovf,
                          const uint32_t* __restrict__ ovfCount, float* __restrict__ feat) {
    uint32_t n = *ovfCount;
    for (uint32_t i = blockIdx.x * blockDim.x + threadIdx.x; i < n;
         i += gridDim.x * blockDim.x) {
        uint2 e = ovf[i];
        const float4* src = (const float4*)(tfeat + (size_t)e.x * 32);
        float* dst = feat + (size_t)e.y * 32;
        #pragma unroll
        for (int q = 0; q < 8; ++q) {
            float4 f = src[q];
            atomicAdd(dst + q * 4 + 0, f.x);
            atomicAdd(dst + q * 4 + 1, f.y);
            atomicAdd(dst + q * 4 + 2, f.z);
            atomicAdd(dst + q * 4 + 3, f.w);
        }
    }
}

extern "C" void kernel_launch(void* const* d_in, const int* in_sizes, int n_in,
                              void* d_out, int out_size, void* d_ws, size_t ws_size,
                              hipStream_t stream) {
    const float* tfeat = (const float*)d_in[0];
    const int*   tidx  = (const int*)d_in[1];
    const int*   sidx  = (const int*)d_in[2];

    const int NT = in_sizes[1] / 4;
    const int NS = in_sizes[2] / 4;

    float* feat = (float*)d_out;                        // [NS, 32]
    float* outI = (float*)d_out + (size_t)NS * 32;      // [NS, 4] as floats

    // workspace: [words 21.5MB][cnt NS*4][ovfCount 4 + pad 4] <- one contiguous zero-fill
    //            [groupSum 656*4][prefixArr 10.7MB][ovf NT*8]    (~50MB << ~1GB ws)
    char* base = (char*)d_ws;
    u64*      words    = (u64*)base;
    uint32_t* cnt      = (uint32_t*)(base + (size_t)NWORDS * 8);
    uint32_t* ovfCount = cnt + NS;
    size_t    zeroBytes = (size_t)NWORDS * 8 + (size_t)NS * 4 + 8;
    uint32_t* groupSum  = ovfCount + 2;
    uint32_t* prefixArr = groupSum + NGROUPS;
    uint2*    ovf       = (uint2*)(prefixArr + NWORDS);

    hipMemsetAsync(d_ws, 0, zeroBytes, stream);

    set_bits<<<(NS + 255) / 256, 256, 0, stream>>>(sidx, words, NS);
    group_popcount<<<NGROUPS, 256, 0, stream>>>(words, groupSum);
    word_prefix_indice<<<NGROUPS, 256, 0, stream>>>(words, groupSum, prefixArr, outI);
    teacher_fused<<<(NT + 255) / 256, 256, 0, stream>>>(tidx, tfeat, words, prefixArr, cnt,
                                                        ovf, ovfCount, feat, NT);
    drain_ovf<<<512, 256, 0, stream>>>(tfeat, ovf, ovfCount, feat);
}

// Round 14
// 196.901 us; speedup vs baseline: 1.4668x; 1.0804x over previous
//
#include <hip/hip_runtime.h>
#include <stdint.h>

typedef unsigned long long u64;

// key: ((b*41+z)<<20) | y<<10 | x   (b<4, z<41, y,x<1024)
// -> 164*2^20 = 171,966,464 keys; monotone-equivalent to reference hash
// b*1025^3+z*1025^2+y*1025+x (lex order (b,z,y,x) preserved, bijective).
#define NWORDS 2686976u             // 164*2^20/64 words
#define GW 4096u                    // words per block (256 thr x 16 words)
#define NGROUPS 656u                // NWORDS/GW (exact)

__device__ __forceinline__ uint32_t pack4(int4 v) {
    // v = (b, z, y, x)
    return (((uint32_t)v.x * 41u + (uint32_t)v.y) << 20) |
           ((uint32_t)v.z << 10) | (uint32_t)v.w;
}

// ---------------- phase 1: presence bits ----------------
// Fire-and-forget atomicOr only (round-6 lesson: no contended counters, no return use).
// words[] is a bare u64 bitmap (21.5 MB) — round-13: split word/prefix arrays halve
// every table pass; the probe's two loads are address-independent anyway.
__global__ void set_bits(const int* __restrict__ sidx, u64* __restrict__ words, int ns) {
    int i = blockIdx.x * blockDim.x + threadIdx.x;
    if (i >= ns) return;
    uint32_t k = pack4(((const int4*)sidx)[i]);
    atomicOr(&words[k >> 6], 1ull << (k & 63u));
}

// ---------------- phase 2: per-group bit counts (wave-coalesced streaming reads) ----------------
__global__ void group_popcount(const u64* __restrict__ words, uint32_t* __restrict__ groupSum) {
    __shared__ uint32_t s[256];
    uint32_t t = 0;
    size_t base = (size_t)blockIdx.x * GW;
    #pragma unroll
    for (int j = 0; j < 16; ++j)
        t += (uint32_t)__popcll(words[base + j * 256u + threadIdx.x]);
    s[threadIdx.x] = t;
    __syncthreads();
    #pragma unroll
    for (int off = 128; off > 0; off >>= 1) {
        if (threadIdx.x < (unsigned)off) s[threadIdx.x] += s[threadIdx.x + off];
        __syncthreads();
    }
    if (threadIdx.x == 0) groupSum[blockIdx.x] = s[0];
}

// ---------------- phase 3: per-word prefix + sorted decoded indice ----------------
// groupSum entries are FINALIZED by the kernel boundary (round-10 lesson: no
// intra-kernel cross-XCD producer-consumer spin). prefixArr writes are dense
// coalesced lines; words[] is read-only here.
__global__ void word_prefix_indice(const u64* __restrict__ words,
                                   const uint32_t* __restrict__ groupSum,
                                   uint32_t* __restrict__ prefixArr,
                                   float* __restrict__ outI) {
    __shared__ uint32_t s[256];
    __shared__ uint32_t baseSh;
    const int tid = threadIdx.x, bid = blockIdx.x;
    size_t w0 = (size_t)bid * GW + (size_t)tid * 16;
    u64 w[16];
    uint32_t tsum = 0;
    #pragma unroll
    for (int j = 0; j < 16; ++j) { w[j] = words[w0 + j]; tsum += (uint32_t)__popcll(w[j]); }
    s[tid] = tsum;
    __syncthreads();
    #pragma unroll
    for (int off = 1; off < 256; off <<= 1) {
        uint32_t u = (tid >= off) ? s[tid - off] : 0u;
        __syncthreads();
        s[tid] += u;
        __syncthreads();
    }
    uint32_t exclInBlock = s[tid] - tsum;
    // wave 0: sum of preceding blocks' totals (empty loop for bid==0 -> 0)
    if (tid < 64) {
        uint32_t sum = 0;
        for (int g = tid; g < bid; g += 64) sum += groupSum[g];
        #pragma unroll
        for (int off = 32; off > 0; off >>= 1) sum += __shfl_down(sum, off);
        if (tid == 0) baseSh = sum;
    }
    __syncthreads();
    uint32_t run = baseSh + exclInBlock;   // exclusive rank at this thread's first word
    #pragma unroll
    for (int j = 0; j < 16; ++j) {
        prefixArr[w0 + j] = run;
        u64 word = w[j];
        uint32_t kw = (uint32_t)(w0 + j) << 6;
        while (word) {
            int b = (int)__builtin_ctzll(word);
            word &= word - 1;
            uint32_t k = kw | (uint32_t)b;
            uint32_t bz = k >> 20;
            ((float4*)outI)[run++] = make_float4(
                (float)(bz / 41u), (float)(bz % 41u),
                (float)((k >> 10) & 1023u), (float)(k & 1023u));
        }
    }
}

// ---------------- phase 4: fused teacher pass — compact claims, then move cooperatively ----
// Phase A (per-thread): probe (2 independent random loads) + claim atomic; winners
// record (t,p) into an LDS compaction buffer. Losers (~46K of 2M) append to the
// global overflow list. NO feature bytes touched here -> low VGPR, claim latency
// decoupled from the move.
// Phase B (per-wave): move claimed rows 8-per-wave-issue — lanes (sub=lane>>3,
// fidx=lane&7) give each row 8 lanes x float4 = 128B, 100% lane-active, fully
// coalesced per row. LDS compaction order is nondeterministic but the SET is
// deterministic and each row is moved exactly once -> deterministic output.
__global__ void teacher_fused(const int* __restrict__ tidx, const float* __restrict__ tfeat,
                              const u64* __restrict__ words, const uint32_t* __restrict__ prefixArr,
                              uint32_t* __restrict__ cnt,
                              uint2* __restrict__ ovf, uint32_t* __restrict__ ovfCount,
                              float* __restrict__ feat, int nt) {
    __shared__ uint32_t sT[256];
    __shared__ uint32_t sP[256];
    __shared__ uint32_t sCount;
    const int tid = threadIdx.x;
    int t = blockIdx.x * 256 + tid;

    if (tid == 0) sCount = 0u;
    __syncthreads();

    if (t < nt) {
        uint32_t k = pack4(((const int4*)tidx)[t]);
        u64 word = words[k >> 6];                 // independent random loads
        uint32_t pfx = prefixArr[k >> 6];
        u64 bit = 1ull << (k & 63u);
        if (word & bit) {
            uint32_t p = pfx + (uint32_t)__popcll(word & (bit - 1ull));
            uint32_t old = atomicAdd(&cnt[p], 1u);
            if (old == 0u) {
                uint32_t i = atomicAdd(&sCount, 1u);   // LDS atomic: cheap
                sT[i] = (uint32_t)t;
                sP[i] = p;
            } else {
                uint32_t idx = atomicAdd(ovfCount, 1u);
                ovf[idx] = make_uint2((uint32_t)t, p);
            }
        }
    }
    __syncthreads();

    // phase B: wave-cooperative move, 8 rows per wave iteration, 16B per lane
    uint32_t n = sCount;
    int lane = tid & 63;
    int wid  = tid >> 6;                  // 4 waves
    int sub  = lane >> 3;                 // row slot within wave (0..7)
    int fidx = lane & 7;                  // float4 index within row (0..7)
    for (uint32_t r = (uint32_t)(wid * 8 + sub); r < n; r += 32u) {
        uint32_t tt = sT[r], pp = sP[r];
        float4 v = ((const float4*)(tfeat + (size_t)tt * 32))[fidx];
        ((float4*)(feat + (size_t)pp * 32))[fidx] = v;
    }
}

// ---------------- phase 5: drain overflow (rare duplicate contributors) ----------------
__global__ void drain_ovf(const float* __restrict__ tfeat, const uint2* __restrict__ ovf,
                          const uint32_t* __restrict__ ovfCount, float* __restrict__ feat) {
    uint32_t n = *ovfCount;
    for (uint32_t i = blockIdx.x * blockDim.x + threadIdx.x; i < n;
         i += gridDim.x * blockDim.x) {
        uint2 e = ovf[i];
        const float4* src = (const float4*)(tfeat + (size_t)e.x * 32);
        float* dst = feat + (size_t)e.y * 32;
        #pragma unroll
        for (int q = 0; q < 8; ++q) {
            float4 f = src[q];
            atomicAdd(dst + q * 4 + 0, f.x);
            atomicAdd(dst + q * 4 + 1, f.y);
            atomicAdd(dst + q * 4 + 2, f.z);
            atomicAdd(dst + q * 4 + 3, f.w);
        }
    }
}

extern "C" void kernel_launch(void* const* d_in, const int* in_sizes, int n_in,
                              void* d_out, int out_size, void* d_ws, size_t ws_size,
                              hipStream_t stream) {
    const float* tfeat = (const float*)d_in[0];
    const int*   tidx  = (const int*)d_in[1];
    const int*   sidx  = (const int*)d_in[2];

    const int NT = in_sizes[1] / 4;
    const int NS = in_sizes[2] / 4;

    float* feat = (float*)d_out;                        // [NS, 32]
    float* outI = (float*)d_out + (size_t)NS * 32;      // [NS, 4] as floats

    // workspace: [words 21.5MB][cnt NS*4][ovfCount 4 + pad 4] <- one contiguous zero-fill
    //            [groupSum 656*4][prefixArr 10.7MB][ovf NT*8]    (~50MB << ~1GB ws)
    char* base = (char*)d_ws;
    u64*      words    = (u64*)base;
    uint32_t* cnt      = (uint32_t*)(base + (size_t)NWORDS * 8);
    uint32_t* ovfCount = cnt + NS;
    size_t    zeroBytes = (size_t)NWORDS * 8 + (size_t)NS * 4 + 8;
    uint32_t* groupSum  = ovfCount + 2;
    uint32_t* prefixArr = groupSum + NGROUPS;
    uint2*    ovf       = (uint2*)(prefixArr + NWORDS);

    hipMemsetAsync(d_ws, 0, zeroBytes, stream);

    set_bits<<<(NS + 255) / 256, 256, 0, stream>>>(sidx, words, NS);
    group_popcount<<<NGROUPS, 256, 0, stream>>>(words, groupSum);
    word_prefix_indice<<<NGROUPS, 256, 0, stream>>>(words, groupSum, prefixArr, outI);
    teacher_fused<<<(NT + 255) / 256, 256, 0, stream>>>(tidx, tfeat, words, prefixArr, cnt,
                                                        ovf, ovfCount, feat, NT);
    drain_ovf<<<512, 256, 0, stream>>>(tfeat, ovf, ovfCount, feat);
}